// Round 1
// baseline (342.479 us; speedup 1.0000x reference)
//
#include <hip/hip_runtime.h>

#define LSIZE 24
#define VOL (LSIZE*LSIZE*LSIZE*LSIZE)       // 331776 sites
#define NLINES (LSIZE*LSIZE*LSIZE)          // 13824 lines per direction
#define NTHREADS (4*NLINES)                 // 55296 one thread per line

__device__ __forceinline__ void load9(const float* __restrict__ p, float* r) {
#pragma unroll
  for (int e = 0; e < 9; ++e) r[e] = p[e];
}
__device__ __forceinline__ void store9(float* __restrict__ p, const float* r) {
#pragma unroll
  for (int e = 0; e < 9; ++e) p[e] = r[e];
}
__device__ __forceinline__ void copy9(float* d, const float* s) {
#pragma unroll
  for (int e = 0; e < 9; ++e) d[e] = s[e];
}

// (o_re,o_im) = a * b, complex 3x3 matmul (row-major)
__device__ __forceinline__ void cmul(const float* ar, const float* ai,
                                     const float* br, const float* bi,
                                     float* or_, float* oi_) {
#pragma unroll
  for (int i = 0; i < 3; ++i) {
#pragma unroll
    for (int j = 0; j < 3; ++j) {
      float sr = 0.f, si = 0.f;
#pragma unroll
      for (int m = 0; m < 3; ++m) {
        float x = ar[i*3+m], y = ai[i*3+m];
        float u = br[m*3+j], v = bi[m*3+j];
        sr = fmaf(x, u, sr);
        sr = fmaf(-y, v, sr);
        si = fmaf(x, v, si);
        si = fmaf(y, u, si);
      }
      or_[i*3+j] = sr;
      oi_[i*3+j] = si;
    }
  }
}

// One thread per (direction, line). Pass 1: prefix products A_k staged into
// the output slots. Pass 2 (descending): P(k) = B_k * A_{k-1}, overwrite slot.
// P(0) = A_23 kept in registers, written last.
__global__ __launch_bounds__(256) void polyakov(
    const float* __restrict__ U_re, const float* __restrict__ U_im,
    float* __restrict__ out) {
  int t = blockIdx.x * 256 + threadIdx.x;
  if (t >= NTHREADS) return;
  int mu = t / NLINES;
  int l  = t - mu * NLINES;
  int cC = l % LSIZE;
  int cB = (l / LSIZE) % LSIZE;
  int cA = l / (LSIZE*LSIZE);

  int x0, x1, x2, x3, st;
  if (mu == 0)      { x0 = 0;  x1 = cA; x2 = cB; x3 = cC; st = LSIZE*LSIZE*LSIZE; }
  else if (mu == 1) { x0 = cA; x1 = 0;  x2 = cB; x3 = cC; st = LSIZE*LSIZE; }
  else if (mu == 2) { x0 = cA; x1 = cB; x2 = 0;  x3 = cC; st = LSIZE; }
  else              { x0 = cA; x1 = cB; x2 = cC; x3 = 0;  st = 1; }
  int s0 = ((x0*LSIZE + x1)*LSIZE + x2)*LSIZE + x3;

  const float* inR = U_re + mu*(VOL*9);
  const float* inI = U_im + mu*(VOL*9);
  float* outR = out + mu*(VOL*9);
  float* outI = out + 4*(VOL*9) + mu*(VOL*9);

  float Ar[9], Ai[9], Tr[9], Ti[9];
  float Ucr[9], Uci[9], Unr[9], Uni[9];

  // ---- Pass 1: prefix products A_k -> out slots ----
  {
    int idx0 = s0 * 9;
    load9(inR + idx0, Ar); load9(inI + idx0, Ai);
    store9(outR + idx0, Ar); store9(outI + idx0, Ai);
    int idx1 = (s0 + st) * 9;
    load9(inR + idx1, Unr); load9(inI + idx1, Uni);   // prefetch U_1
    for (int k = 1; k < LSIZE; ++k) {
      copy9(Ucr, Unr); copy9(Uci, Uni);
      if (k + 1 < LSIZE) {
        int idxn = (s0 + (k + 1) * st) * 9;
        load9(inR + idxn, Unr); load9(inI + idxn, Uni);
      }
      cmul(Ar, Ai, Ucr, Uci, Tr, Ti);
      copy9(Ar, Tr); copy9(Ai, Ti);
      int idxk = (s0 + k * st) * 9;
      store9(outR + idxk, Ar); store9(outI + idxk, Ai);
    }
  }
  // A = A_23 = full product = P(0); keep live.
  float Pr[9], Pi[9];
  copy9(Pr, Ar); copy9(Pi, Ai);

  // ---- Pass 2: suffix descending ----
  {
    float Br[9], Bi[9], Qr[9], Qi[9], Qnr[9], Qni[9];
    int idx23 = (s0 + 23 * st) * 9;
    load9(inR + idx23, Br); load9(inI + idx23, Bi);     // B_23 = U_23
    int idx22 = (s0 + 22 * st) * 9;
    load9(outR + idx22, Qnr); load9(outI + idx22, Qni); // A_22
    load9(inR + idx22, Unr); load9(inI + idx22, Uni);   // U_22
    for (int k = 23; k >= 1; --k) {
      copy9(Qr, Qnr); copy9(Qi, Qni);
      copy9(Ucr, Unr); copy9(Uci, Uni);
      if (k >= 2) {
        int idxp = (s0 + (k - 2) * st) * 9;
        load9(outR + idxp, Qnr); load9(outI + idxp, Qni); // A_{k-2}
        load9(inR + idxp, Unr); load9(inI + idxp, Uni);   // U_{k-2}
      }
      cmul(Br, Bi, Qr, Qi, Tr, Ti);        // P(k) = B_k * A_{k-1}
      int idxk = (s0 + k * st) * 9;
      store9(outR + idxk, Tr); store9(outI + idxk, Ti);
      cmul(Ucr, Uci, Br, Bi, Tr, Ti);      // B_{k-1} = U_{k-1} * B_k
      copy9(Br, Tr); copy9(Bi, Ti);
    }
    int idx0 = s0 * 9;
    store9(outR + idx0, Pr); store9(outI + idx0, Pi);   // P(0)
  }
}

extern "C" void kernel_launch(void* const* d_in, const int* in_sizes, int n_in,
                              void* d_out, int out_size, void* d_ws, size_t ws_size,
                              hipStream_t stream) {
  const float* U_re = (const float*)d_in[0];
  const float* U_im = (const float*)d_in[1];
  float* out = (float*)d_out;
  dim3 grid(NTHREADS / 256), block(256);
  hipLaunchKernelGGL(polyakov, grid, block, 0, stream, U_re, U_im, out);
}

// Round 2
// 225.445 us; speedup vs baseline: 1.5191x; 1.5191x over previous
//
#include <hip/hip_runtime.h>

#define LSIZE 24
#define VOL (LSIZE*LSIZE*LSIZE*LSIZE)       // 331776 sites
#define NLINES (LSIZE*LSIZE*LSIZE)          // 13824 lines per direction
#define LPB 8                               // lines per block
#define TPB (LPB*LSIZE)                     // 192 threads = 3 waves

__device__ __forceinline__ void copy9(float* d, const float* s) {
#pragma unroll
  for (int e = 0; e < 9; ++e) d[e] = s[e];
}

// (o_re,o_im) = a * b, complex 3x3 matmul (row-major)
__device__ __forceinline__ void cmul(const float* ar, const float* ai,
                                     const float* br, const float* bi,
                                     float* or_, float* oi_) {
#pragma unroll
  for (int i = 0; i < 3; ++i) {
#pragma unroll
    for (int j = 0; j < 3; ++j) {
      float sr = 0.f, si = 0.f;
#pragma unroll
      for (int m = 0; m < 3; ++m) {
        float x = ar[i*3+m], y = ai[i*3+m];
        float u = br[m*3+j], v = bi[m*3+j];
        sr = fmaf(x, u, sr);
        sr = fmaf(-y, v, sr);
        si = fmaf(x, v, si);
        si = fmaf(y, u, si);
      }
      or_[i*3+j] = sr;
      oi_[i*3+j] = si;
    }
  }
}

__device__ __forceinline__ void lds_put(float* lds, int slot, const float* re, const float* im) {
  float* p = lds + slot * 18;
#pragma unroll
  for (int e = 0; e < 9; ++e) { p[e] = re[e]; p[9+e] = im[e]; }
}
__device__ __forceinline__ void lds_get(const float* lds, int slot, float* re, float* im) {
  const float* p = lds + slot * 18;
#pragma unroll
  for (int e = 0; e < 9; ++e) { re[e] = p[e]; im[e] = p[9+e]; }
}

// One thread per (direction, line, offset k). Per line: Hillis-Steele prefix
// scan A_k = U_0..U_k and suffix scan S_k = U_k..U_23 in LDS, then
// P(k) = S_k * A_{k-1} (A_{-1} = I).
__global__ __launch_bounds__(TPB, 4) void polyakov_scan(
    const float* __restrict__ U_re, const float* __restrict__ U_im,
    float* __restrict__ out) {
  __shared__ float lds[LPB * LSIZE * 18];   // 13824 B

  int tid = threadIdx.x;
  int lineLocal = tid % LPB;    // fast index -> coalesced global access
  int k = tid / LPB;            // offset along the line, 0..23
  int L = blockIdx.x * LPB + lineLocal;
  int mu = L / NLINES;
  int l  = L - mu * NLINES;
  int cC = l % LSIZE;
  int cB = (l / LSIZE) % LSIZE;
  int cA = l / (LSIZE*LSIZE);

  int x0, x1, x2, x3, st;
  if (mu == 0)      { x0 = 0;  x1 = cA; x2 = cB; x3 = cC; st = LSIZE*LSIZE*LSIZE; }
  else if (mu == 1) { x0 = cA; x1 = 0;  x2 = cB; x3 = cC; st = LSIZE*LSIZE; }
  else if (mu == 2) { x0 = cA; x1 = cB; x2 = 0;  x3 = cC; st = LSIZE; }
  else              { x0 = cA; x1 = cB; x2 = cC; x3 = 0;  st = 1; }
  int s0 = ((x0*LSIZE + x1)*LSIZE + x2)*LSIZE + x3;
  int site = s0 + k * st;

  const float* inR = U_re + (size_t)mu * (VOL*9) + (size_t)site * 9;
  const float* inI = U_im + (size_t)mu * (VOL*9) + (size_t)site * 9;

  float Ur[9], Ui[9];
#pragma unroll
  for (int e = 0; e < 9; ++e) { Ur[e] = inR[e]; Ui[e] = inI[e]; }

  int slot = lineLocal * LSIZE + k;
  float Ar[9], Ai[9], Br[9], Bi[9], Tr[9], Ti[9];

  // ---- prefix scan: A_k = U_0 ... U_k ----
  copy9(Ar, Ur); copy9(Ai, Ui);
#pragma unroll
  for (int d = 1; d < LSIZE; d <<= 1) {
    lds_put(lds, slot, Ar, Ai);
    __syncthreads();
    if (k >= d) lds_get(lds, lineLocal * LSIZE + (k - d), Br, Bi);
    __syncthreads();
    if (k >= d) {
      cmul(Br, Bi, Ar, Ai, Tr, Ti);   // A_new = A[k-d] * A[k]
      copy9(Ar, Tr); copy9(Ai, Ti);
    }
  }
  // publish final prefixes, grab A_{k-1}
  lds_put(lds, slot, Ar, Ai);
  __syncthreads();
  float Apr[9], Api[9];
  if (k >= 1) {
    lds_get(lds, lineLocal * LSIZE + (k - 1), Apr, Api);
  } else {
#pragma unroll
    for (int e = 0; e < 9; ++e) { Apr[e] = (e == 0 || e == 4 || e == 8) ? 1.f : 0.f; Api[e] = 0.f; }
  }
  __syncthreads();

  // ---- suffix scan: S_k = U_k ... U_23 (reuse Ar/Ai as S) ----
  copy9(Ar, Ur); copy9(Ai, Ui);
#pragma unroll
  for (int d = 1; d < LSIZE; d <<= 1) {
    lds_put(lds, slot, Ar, Ai);
    __syncthreads();
    if (k + d < LSIZE) lds_get(lds, lineLocal * LSIZE + (k + d), Br, Bi);
    __syncthreads();
    if (k + d < LSIZE) {
      cmul(Ar, Ai, Br, Bi, Tr, Ti);   // S_new = S[k] * S[k+d]
      copy9(Ar, Tr); copy9(Ai, Ti);
    }
  }

  // ---- P(k) = S_k * A_{k-1} ----
  cmul(Ar, Ai, Apr, Api, Tr, Ti);

  float* outR = out + (size_t)mu * (VOL*9) + (size_t)site * 9;
  float* outI = out + (size_t)(4 + mu) * (VOL*9) + (size_t)site * 9;
#pragma unroll
  for (int e = 0; e < 9; ++e) { outR[e] = Tr[e]; outI[e] = Ti[e]; }
}

extern "C" void kernel_launch(void* const* d_in, const int* in_sizes, int n_in,
                              void* d_out, int out_size, void* d_ws, size_t ws_size,
                              hipStream_t stream) {
  const float* U_re = (const float*)d_in[0];
  const float* U_im = (const float*)d_in[1];
  float* out = (float*)d_out;
  int nblocks = 4 * NLINES / LPB;   // 6912
  hipLaunchKernelGGL(polyakov_scan, dim3(nblocks), dim3(TPB), 0, stream, U_re, U_im, out);
}